// Round 1
// baseline (263.791 us; speedup 1.0000x reference)
//
#include <hip/hip_runtime.h>
#include <math.h>

#define NQ 6
#define DIM 64
#define DEPTH 2

__global__ __launch_bounds__(256) void qent_kernel(
    const float* __restrict__ x,
    const float* __restrict__ theta,
    const float* __restrict__ phi,
    const float* __restrict__ omega,
    float* __restrict__ out, int n)
{
    // ---- per-block: compute the 12 fused gates V = RX*RY*RZ into LDS ----
    __shared__ float g[DEPTH][NQ][8]; // {V00r,V00i,V01r,V01i,V10r,V10i,V11r,V11i}
    int tid = threadIdx.x;
    if (tid < DEPTH * NQ) {
        int l = tid / NQ, w = tid % NQ;
        float th = theta[l * NQ + w] * 0.5f;
        float ph = phi[l * NQ + w] * 0.5f;
        float om = omega[l * NQ + w] * 0.5f;
        float st, ct, sp, cp, so, co;
        sincosf(th, &st, &ct);
        sincosf(ph, &sp, &cp);
        sincosf(om, &so, &co);
        // A = RY * RZ ; RZ = diag((ct,-st), (ct,st))
        float A00r = cp * ct, A00i = -cp * st;
        float A01r = -sp * ct, A01i = -sp * st;
        float A10r = sp * ct, A10i = -sp * st;
        float A11r = cp * ct, A11i = cp * st;
        // V = RX * A ; RX = [[co, -i so], [-i so, co]]
        float* G = g[l][w];
        G[0] = co * A00r + so * A10i;  G[1] = co * A00i - so * A10r;  // V00
        G[2] = co * A01r + so * A11i;  G[3] = co * A01i - so * A11r;  // V01
        G[4] = so * A00i + co * A10r;  G[5] = -so * A00r + co * A10i; // V10
        G[6] = so * A01i + co * A11r;  G[7] = -so * A01r + co * A11i; // V11
    }
    __syncthreads();

    int b = blockIdx.x * blockDim.x + tid;
    if (b >= n) return;

    // ---- load x, angle-encode: per-wire (c,s) = (cos(f/2), sin(f/2)), f = tanh(x)*pi ----
    const float2* xr = (const float2*)(x + b * 6);
    float2 x01 = xr[0], x23 = xr[1], x45 = xr[2];
    float xs[6] = {x01.x, x01.y, x23.x, x23.y, x45.x, x45.y};

    // layer-1 fused gate applied to each wire's local (real) 2-vector
    float u0r[NQ], u0i[NQ], u1r[NQ], u1i[NQ];
    #pragma unroll
    for (int w = 0; w < NQ; ++w) {
        float xv = fminf(fmaxf(xs[w], -15.f), 15.f);
        float e = __expf(2.f * xv);
        float t = (e - 1.f) / (e + 1.f);       // tanh
        float a = t * 1.57079632679489662f;    // half-angle = tanh*pi/2
        float s, c;
        __sincosf(a, &s, &c);
        const float* G = g[0][w];
        u0r[w] = G[0] * c + G[2] * s;  u0i[w] = G[1] * c + G[3] * s;
        u1r[w] = G[4] * c + G[6] * s;  u1i[w] = G[5] * c + G[7] * s;
    }

    // ---- build 64-amp product state; wire w lives at bit (5-w) (wire0 = MSB) ----
    float re[DIM], im[DIM];
    re[0] = u0r[0]; im[0] = u0i[0];
    re[1] = u1r[0]; im[1] = u1i[0];
    #pragma unroll
    for (int w = 1; w < NQ; ++w) {
        const int sz = 1 << w;
        #pragma unroll
        for (int k = sz - 1; k >= 0; --k) {
            float ar = re[k], ai = im[k];
            re[2 * k]     = ar * u0r[w] - ai * u0i[w];
            im[2 * k]     = ar * u0i[w] + ai * u0r[w];
            re[2 * k + 1] = ar * u1r[w] - ai * u1i[w];
            im[2 * k + 1] = ar * u1i[w] + ai * u1r[w];
        }
    }

    // CNOT = compile-time register permutation
    auto cnot = [&](int cb, int tb) {
        #pragma unroll
        for (int i = 0; i < DIM; ++i) {
            if ((i & cb) && !(i & tb)) {
                int j = i + tb;
                float tr = re[i], ti = im[i];
                re[i] = re[j]; im[i] = im[j];
                re[j] = tr;    im[j] = ti;
            }
        }
    };

    // ---- layer 1 CNOT ring ----
    #pragma unroll
    for (int w = 0; w < NQ; ++w) {
        int wn = (w + 1) % NQ;
        cnot(1 << (5 - w), 1 << (5 - wn));
    }

    // ---- layer 2: dense fused gates per wire ----
    #pragma unroll
    for (int w = 0; w < NQ; ++w) {
        const float* G = g[1][w];
        float V00r = G[0], V00i = G[1], V01r = G[2], V01i = G[3];
        float V10r = G[4], V10i = G[5], V11r = G[6], V11i = G[7];
        const int tb = 1 << (5 - w);
        #pragma unroll
        for (int i = 0; i < DIM; ++i) {
            if (!(i & tb)) {
                int j = i + tb;
                float a0r = re[i], a0i = im[i], a1r = re[j], a1i = im[j];
                re[i] = V00r * a0r - V00i * a0i + V01r * a1r - V01i * a1i;
                im[i] = V00r * a0i + V00i * a0r + V01r * a1i + V01i * a1r;
                re[j] = V10r * a0r - V10i * a0i + V11r * a1r - V11i * a1i;
                im[j] = V10r * a0i + V10i * a0r + V11r * a1i + V11i * a1r;
            }
        }
    }

    // ---- layer 2 CNOT ring ----
    #pragma unroll
    for (int w = 0; w < NQ; ++w) {
        int wn = (w + 1) % NQ;
        cnot(1 << (5 - w), 1 << (5 - wn));
    }

    // ---- measurement: p = |amp|^2, two 8-bin marginals, then signed sums ----
    float mhi[8] = {0, 0, 0, 0, 0, 0, 0, 0};
    float mlo[8] = {0, 0, 0, 0, 0, 0, 0, 0};
    #pragma unroll
    for (int i = 0; i < DIM; ++i) {
        float pi = re[i] * re[i] + im[i] * im[i];
        mhi[i >> 3] += pi;
        mlo[i & 7]  += pi;
    }
    // wire0..2 from mhi (bits 2,1,0 of h); wire3..5 from mlo (bits 2,1,0 of l)
    float z0 = (mhi[0] + mhi[1] + mhi[2] + mhi[3]) - (mhi[4] + mhi[5] + mhi[6] + mhi[7]);
    float z1 = (mhi[0] + mhi[1] + mhi[4] + mhi[5]) - (mhi[2] + mhi[3] + mhi[6] + mhi[7]);
    float z2 = (mhi[0] + mhi[2] + mhi[4] + mhi[6]) - (mhi[1] + mhi[3] + mhi[5] + mhi[7]);
    float z3 = (mlo[0] + mlo[1] + mlo[2] + mlo[3]) - (mlo[4] + mlo[5] + mlo[6] + mlo[7]);
    float z4 = (mlo[0] + mlo[1] + mlo[4] + mlo[5]) - (mlo[2] + mlo[3] + mlo[6] + mlo[7]);
    float z5 = (mlo[0] + mlo[2] + mlo[4] + mlo[6]) - (mlo[1] + mlo[3] + mlo[5] + mlo[7]);

    // out[:, k] = z[k % 6], k = 0..7  -> two float4 stores (32B per row, aligned)
    float4* o = (float4*)(out + (size_t)b * 8);
    o[0] = make_float4(z0, z1, z2, z3);
    o[1] = make_float4(z4, z5, z0, z1);
}

extern "C" void kernel_launch(void* const* d_in, const int* in_sizes, int n_in,
                              void* d_out, int out_size, void* d_ws, size_t ws_size,
                              hipStream_t stream) {
    const float* x     = (const float*)d_in[0];
    const float* theta = (const float*)d_in[1];
    const float* phi   = (const float*)d_in[2];
    const float* omega = (const float*)d_in[3];
    float* out = (float*)d_out;
    int n = in_sizes[0] / NQ;
    int blocks = (n + 255) / 256;
    hipLaunchKernelGGL(qent_kernel, dim3(blocks), dim3(256), 0, stream,
                       x, theta, phi, omega, out, n);
}

// Round 2
// 263.350 us; speedup vs baseline: 1.0017x; 1.0017x over previous
//
#include <hip/hip_runtime.h>
#include <math.h>

#define NQ 6
#define DIM 64
#define DEPTH 2

__global__ __launch_bounds__(256, 1) void qent_kernel(
    const float* __restrict__ x,
    const float* __restrict__ theta,
    const float* __restrict__ phi,
    const float* __restrict__ omega,
    float* __restrict__ out, int n)
{
    // ---- per-block: compute the 12 fused gates V = RX*RY*RZ into LDS ----
    __shared__ float g[DEPTH][NQ][8]; // {V00r,V00i,V01r,V01i,V10r,V10i,V11r,V11i}
    int tid = threadIdx.x;
    if (tid < DEPTH * NQ) {
        int l = tid / NQ, w = tid % NQ;
        float th = theta[l * NQ + w] * 0.5f;
        float ph = phi[l * NQ + w] * 0.5f;
        float om = omega[l * NQ + w] * 0.5f;
        float st, ct, sp, cp, so, co;
        sincosf(th, &st, &ct);
        sincosf(ph, &sp, &cp);
        sincosf(om, &so, &co);
        // A = RY * RZ ; RZ = diag((ct,-st), (ct,st))
        float A00r = cp * ct, A00i = -cp * st;
        float A01r = -sp * ct, A01i = -sp * st;
        float A10r = sp * ct, A10i = -sp * st;
        float A11r = cp * ct, A11i = cp * st;
        // V = RX * A ; RX = [[co, -i so], [-i so, co]]
        float* G = g[l][w];
        G[0] = co * A00r + so * A10i;  G[1] = co * A00i - so * A10r;  // V00
        G[2] = co * A01r + so * A11i;  G[3] = co * A01i - so * A11r;  // V01
        G[4] = so * A00i + co * A10r;  G[5] = -so * A00r + co * A10i; // V10
        G[6] = so * A01i + co * A11r;  G[7] = -so * A01r + co * A11i; // V11
    }
    __syncthreads();

    int b = blockIdx.x * blockDim.x + tid;
    if (b >= n) return;

    // ---- load x, angle-encode: per-wire (c,s) = (cos(f/2), sin(f/2)), f = tanh(x)*pi ----
    const float2* xr = (const float2*)(x + b * 6);
    float2 x01 = xr[0], x23 = xr[1], x45 = xr[2];
    float xs[6] = {x01.x, x01.y, x23.x, x23.y, x45.x, x45.y};

    // layer-1 fused gate applied to each wire's local (real) 2-vector
    float u0r[NQ], u0i[NQ], u1r[NQ], u1i[NQ];
    #pragma unroll
    for (int w = 0; w < NQ; ++w) {
        float xv = fminf(fmaxf(xs[w], -15.f), 15.f);
        float e = __expf(2.f * xv);
        float t = (e - 1.f) / (e + 1.f);       // tanh
        float a = t * 1.57079632679489662f;    // half-angle = tanh*pi/2
        float s, c;
        __sincosf(a, &s, &c);
        const float* G = g[0][w];
        u0r[w] = G[0] * c + G[2] * s;  u0i[w] = G[1] * c + G[3] * s;
        u1r[w] = G[4] * c + G[6] * s;  u1i[w] = G[5] * c + G[7] * s;
    }

    // ---- build 64-amp product state; wire w lives at bit (5-w) (wire0 = MSB) ----
    float re[DIM], im[DIM];
    re[0] = u0r[0]; im[0] = u0i[0];
    re[1] = u1r[0]; im[1] = u1i[0];
    #pragma unroll
    for (int w = 1; w < NQ; ++w) {
        const int sz = 1 << w;
        #pragma unroll
        for (int k = sz - 1; k >= 0; --k) {
            float ar = re[k], ai = im[k];
            re[2 * k]     = ar * u0r[w] - ai * u0i[w];
            im[2 * k]     = ar * u0i[w] + ai * u0r[w];
            re[2 * k + 1] = ar * u1r[w] - ai * u1i[w];
            im[2 * k + 1] = ar * u1i[w] + ai * u1r[w];
        }
    }

    // CNOT = compile-time register permutation
    auto cnot = [&](int cb, int tb) {
        #pragma unroll
        for (int i = 0; i < DIM; ++i) {
            if ((i & cb) && !(i & tb)) {
                int j = i + tb;
                float tr = re[i], ti = im[i];
                re[i] = re[j]; im[i] = im[j];
                re[j] = tr;    im[j] = ti;
            }
        }
    };

    // ---- layer 1 CNOT ring ----
    #pragma unroll
    for (int w = 0; w < NQ; ++w) {
        int wn = (w + 1) % NQ;
        cnot(1 << (5 - w), 1 << (5 - wn));
    }

    // ---- layer 2: dense fused gates per wire ----
    #pragma unroll
    for (int w = 0; w < NQ; ++w) {
        const float* G = g[1][w];
        float V00r = G[0], V00i = G[1], V01r = G[2], V01i = G[3];
        float V10r = G[4], V10i = G[5], V11r = G[6], V11i = G[7];
        const int tb = 1 << (5 - w);
        #pragma unroll
        for (int i = 0; i < DIM; ++i) {
            if (!(i & tb)) {
                int j = i + tb;
                float a0r = re[i], a0i = im[i], a1r = re[j], a1i = im[j];
                re[i] = V00r * a0r - V00i * a0i + V01r * a1r - V01i * a1i;
                im[i] = V00r * a0i + V00i * a0r + V01r * a1i + V01i * a1r;
                re[j] = V10r * a0r - V10i * a0i + V11r * a1r - V11i * a1i;
                im[j] = V10r * a0i + V10i * a0r + V11r * a1i + V11i * a1r;
            }
        }
    }

    // ---- layer 2 CNOT ring ----
    #pragma unroll
    for (int w = 0; w < NQ; ++w) {
        int wn = (w + 1) % NQ;
        cnot(1 << (5 - w), 1 << (5 - wn));
    }

    // ---- measurement: p = |amp|^2, two 8-bin marginals, then signed sums ----
    float mhi[8] = {0, 0, 0, 0, 0, 0, 0, 0};
    float mlo[8] = {0, 0, 0, 0, 0, 0, 0, 0};
    #pragma unroll
    for (int i = 0; i < DIM; ++i) {
        float pi = re[i] * re[i] + im[i] * im[i];
        mhi[i >> 3] += pi;
        mlo[i & 7]  += pi;
    }
    // wire0..2 from mhi (bits 2,1,0 of h); wire3..5 from mlo (bits 2,1,0 of l)
    float z0 = (mhi[0] + mhi[1] + mhi[2] + mhi[3]) - (mhi[4] + mhi[5] + mhi[6] + mhi[7]);
    float z1 = (mhi[0] + mhi[1] + mhi[4] + mhi[5]) - (mhi[2] + mhi[3] + mhi[6] + mhi[7]);
    float z2 = (mhi[0] + mhi[2] + mhi[4] + mhi[6]) - (mhi[1] + mhi[3] + mhi[5] + mhi[7]);
    float z3 = (mlo[0] + mlo[1] + mlo[2] + mlo[3]) - (mlo[4] + mlo[5] + mlo[6] + mlo[7]);
    float z4 = (mlo[0] + mlo[1] + mlo[4] + mlo[5]) - (mlo[2] + mlo[3] + mlo[6] + mlo[7]);
    float z5 = (mlo[0] + mlo[2] + mlo[4] + mlo[6]) - (mlo[1] + mlo[3] + mlo[5] + mlo[7]);

    // out[:, k] = z[k % 6], k = 0..7  -> two float4 stores (32B per row, aligned)
    float4* o = (float4*)(out + (size_t)b * 8);
    o[0] = make_float4(z0, z1, z2, z3);
    o[1] = make_float4(z4, z5, z0, z1);
}

extern "C" void kernel_launch(void* const* d_in, const int* in_sizes, int n_in,
                              void* d_out, int out_size, void* d_ws, size_t ws_size,
                              hipStream_t stream) {
    const float* x     = (const float*)d_in[0];
    const float* theta = (const float*)d_in[1];
    const float* phi   = (const float*)d_in[2];
    const float* omega = (const float*)d_in[3];
    float* out = (float*)d_out;
    int n = in_sizes[0] / NQ;
    int blocks = (n + 255) / 256;
    hipLaunchKernelGGL(qent_kernel, dim3(blocks), dim3(256), 0, stream,
                       x, theta, phi, omega, out, n);
}

// Round 3
// 31.255 us; speedup vs baseline: 8.4398x; 8.4257x over previous
//
#include <hip/hip_runtime.h>
#include <math.h>

#define NQ 6
#define DIM 64
#define DEPTH 2

typedef float f64v __attribute__((ext_vector_type(64)));
typedef float f8v  __attribute__((ext_vector_type(8)));

__global__ __launch_bounds__(256, 1) void qent_kernel(
    const float* __restrict__ x,
    const float* __restrict__ theta,
    const float* __restrict__ phi,
    const float* __restrict__ omega,
    float* __restrict__ out, int n)
{
    // ---- per-block: compute the 12 fused gates V = RX*RY*RZ into LDS ----
    __shared__ float g[DEPTH][NQ][8]; // {V00r,V00i,V01r,V01i,V10r,V10i,V11r,V11i}
    int tid = threadIdx.x;
    if (tid < DEPTH * NQ) {
        int l = tid / NQ, w = tid % NQ;
        float th = theta[l * NQ + w] * 0.5f;
        float ph = phi[l * NQ + w] * 0.5f;
        float om = omega[l * NQ + w] * 0.5f;
        float st, ct, sp, cp, so, co;
        sincosf(th, &st, &ct);
        sincosf(ph, &sp, &cp);
        sincosf(om, &so, &co);
        // A = RY * RZ ; RZ = diag((ct,-st), (ct,st))
        float A00r = cp * ct, A00i = -cp * st;
        float A01r = -sp * ct, A01i = -sp * st;
        float A10r = sp * ct, A10i = -sp * st;
        float A11r = cp * ct, A11i = cp * st;
        // V = RX * A ; RX = [[co, -i so], [-i so, co]]
        float* G = g[l][w];
        G[0] = co * A00r + so * A10i;  G[1] = co * A00i - so * A10r;  // V00
        G[2] = co * A01r + so * A11i;  G[3] = co * A01i - so * A11r;  // V01
        G[4] = so * A00i + co * A10r;  G[5] = -so * A00r + co * A10i; // V10
        G[6] = so * A01i + co * A11r;  G[7] = -so * A01r + co * A11i; // V11
    }
    __syncthreads();

    int b = blockIdx.x * blockDim.x + tid;
    if (b >= n) return;

    const float2* xr = (const float2*)(x + (size_t)b * 6);
    float2 x01 = xr[0], x23 = xr[1], x45 = xr[2];

    // ---- state in two 64-wide register vectors; wire w lives at bit (5-w) ----
    f64v re, im;

    // angle-encode + layer-1 fused gate on local 2-vector, then product-expand
    #pragma unroll
    for (int w = 0; w < NQ; ++w) {
        float xv = (w == 0) ? x01.x : (w == 1) ? x01.y : (w == 2) ? x23.x
                 : (w == 3) ? x23.y : (w == 4) ? x45.x : x45.y;
        xv = fminf(fmaxf(xv, -15.f), 15.f);
        float e = __expf(2.f * xv);
        float t = (e - 1.f) / (e + 1.f);       // tanh
        float a = t * 1.57079632679489662f;    // half-angle = tanh*pi/2
        float s, c;
        __sincosf(a, &s, &c);
        const float* G = g[0][w];
        float u0r = G[0] * c + G[2] * s, u0i = G[1] * c + G[3] * s;
        float u1r = G[4] * c + G[6] * s, u1i = G[5] * c + G[7] * s;
        if (w == 0) {
            re[0] = u0r; im[0] = u0i;
            re[1] = u1r; im[1] = u1i;
        } else {
            const int sz = 1 << w;
            #pragma unroll
            for (int k = sz - 1; k >= 0; --k) {
                float ar = re[k], ai = im[k];
                re[2 * k]     = ar * u0r - ai * u0i;
                im[2 * k]     = ar * u0i + ai * u0r;
                re[2 * k + 1] = ar * u1r - ai * u1i;
                im[2 * k + 1] = ar * u1i + ai * u1r;
            }
        }
    }

    // ---- layer 1 CNOT ring (compile-time register permutation) ----
    #pragma unroll
    for (int w = 0; w < NQ; ++w) {
        const int cb = 1 << (5 - w), tb = 1 << (5 - ((w + 1) % NQ));
        #pragma unroll
        for (int i = 0; i < DIM; ++i) {
            if ((i & cb) && !(i & tb)) {
                const int j = i + tb;
                float tr = re[i], ti = im[i];
                re[i] = re[j]; im[i] = im[j];
                re[j] = tr;    im[j] = ti;
            }
        }
    }

    // ---- layer 2: dense fused gates per wire ----
    #pragma unroll
    for (int w = 0; w < NQ; ++w) {
        const float* G = g[1][w];
        float V00r = G[0], V00i = G[1], V01r = G[2], V01i = G[3];
        float V10r = G[4], V10i = G[5], V11r = G[6], V11i = G[7];
        const int tb = 1 << (5 - w);
        #pragma unroll
        for (int i = 0; i < DIM; ++i) {
            if (!(i & tb)) {
                const int j = i + tb;
                float a0r = re[i], a0i = im[i], a1r = re[j], a1i = im[j];
                re[i] = V00r * a0r - V00i * a0i + V01r * a1r - V01i * a1i;
                im[i] = V00r * a0i + V00i * a0r + V01r * a1i + V01i * a1r;
                re[j] = V10r * a0r - V10i * a0i + V11r * a1r - V11i * a1i;
                im[j] = V10r * a0i + V10i * a0r + V11r * a1i + V11i * a1r;
            }
        }
    }

    // ---- layer 2 CNOT ring ----
    #pragma unroll
    for (int w = 0; w < NQ; ++w) {
        const int cb = 1 << (5 - w), tb = 1 << (5 - ((w + 1) % NQ));
        #pragma unroll
        for (int i = 0; i < DIM; ++i) {
            if ((i & cb) && !(i & tb)) {
                const int j = i + tb;
                float tr = re[i], ti = im[i];
                re[i] = re[j]; im[i] = im[j];
                re[j] = tr;    im[j] = ti;
            }
        }
    }

    // ---- measurement: p = |amp|^2, two 8-bin marginals ----
    f8v mhi = {0, 0, 0, 0, 0, 0, 0, 0};
    f8v mlo = {0, 0, 0, 0, 0, 0, 0, 0};
    #pragma unroll
    for (int i = 0; i < DIM; ++i) {
        float p = re[i] * re[i] + im[i] * im[i];
        mhi[i >> 3] += p;
        mlo[i & 7]  += p;
    }
    // wire0..2 from mhi (bits 2,1,0 of high index); wire3..5 from mlo
    float z0 = (mhi[0] + mhi[1] + mhi[2] + mhi[3]) - (mhi[4] + mhi[5] + mhi[6] + mhi[7]);
    float z1 = (mhi[0] + mhi[1] + mhi[4] + mhi[5]) - (mhi[2] + mhi[3] + mhi[6] + mhi[7]);
    float z2 = (mhi[0] + mhi[2] + mhi[4] + mhi[6]) - (mhi[1] + mhi[3] + mhi[5] + mhi[7]);
    float z3 = (mlo[0] + mlo[1] + mlo[2] + mlo[3]) - (mlo[4] + mlo[5] + mlo[6] + mlo[7]);
    float z4 = (mlo[0] + mlo[1] + mlo[4] + mlo[5]) - (mlo[2] + mlo[3] + mlo[6] + mlo[7]);
    float z5 = (mlo[0] + mlo[2] + mlo[4] + mlo[6]) - (mlo[1] + mlo[3] + mlo[5] + mlo[7]);

    // out[:, k] = z[k % 6], k = 0..7
    float4* o = (float4*)(out + (size_t)b * 8);
    o[0] = make_float4(z0, z1, z2, z3);
    o[1] = make_float4(z4, z5, z0, z1);
}

extern "C" void kernel_launch(void* const* d_in, const int* in_sizes, int n_in,
                              void* d_out, int out_size, void* d_ws, size_t ws_size,
                              hipStream_t stream) {
    const float* x     = (const float*)d_in[0];
    const float* theta = (const float*)d_in[1];
    const float* phi   = (const float*)d_in[2];
    const float* omega = (const float*)d_in[3];
    float* out = (float*)d_out;
    int n = in_sizes[0] / NQ;
    int blocks = (n + 255) / 256;
    hipLaunchKernelGGL(qent_kernel, dim3(blocks), dim3(256), 0, stream,
                       x, theta, phi, omega, out, n);
}

// Round 4
// 17.551 us; speedup vs baseline: 15.0300x; 1.7808x over previous
//
#include <hip/hip_runtime.h>
#include <math.h>

#define NQ 6
#define DIM 64

typedef float f2   __attribute__((ext_vector_type(2)));
typedef float f16v __attribute__((ext_vector_type(16)));
typedef float f128 __attribute__((ext_vector_type(128)));

#define F2FMA(a, b, c) __builtin_elementwise_fma((a), (b), (c))

// ---- compile-time CNOT-ring permutations ----
// P[l] = physical register slot holding logical amplitude l.
// CNOT(c,t): A'[l] = A[tau(l)]  =>  P' = P o tau (no data movement).
struct Perms {
    int P1[DIM];  // after layer-1 ring (used by layer-2 gate indexing)
    int P2[DIM];  // after layer-2 ring (used by measurement)
    static constexpr int tau(int l, int c) {
        const int t  = (c + 1) % NQ;
        const int cb = 1 << (5 - c), tb = 1 << (5 - t);
        return (l & cb) ? (l ^ tb) : l;
    }
    static constexpr int ring(int l) {
        // sequential CNOT(w, w+1) for w=0..5 composes to tau0(tau1(...tau5(l)))
        for (int w = NQ - 1; w >= 0; --w) l = tau(l, w);
        return l;
    }
    constexpr Perms() : P1(), P2() {
        for (int l = 0; l < DIM; ++l) P1[l] = ring(l);
        for (int l = 0; l < DIM; ++l) P2[l] = P1[ring(l)];
    }
};
constexpr Perms PP;

__global__ __launch_bounds__(256, 1) void qent_kernel(
    const float* __restrict__ x,
    const float* __restrict__ theta,
    const float* __restrict__ phi,
    const float* __restrict__ omega,
    float* __restrict__ out, int n)
{
    // ---- per-block: fused gates V = RX*RY*RZ ----
    // g8[w]  : layer-1 gate, {V00r,V00i,V01r,V01i,V10r,V10i,V11r,V11i}
    // gp[w]  : layer-2 gate packed for pk-math: {Vr,Vr,-Vi,Vi} x {00,01,10,11}
    __shared__ float g8[NQ][8];
    __shared__ float gp[NQ][16];
    int tid = threadIdx.x;
    if (tid < 2 * NQ) {
        int l = tid / NQ, w = tid % NQ;
        float th = theta[l * NQ + w] * 0.5f;
        float ph = phi[l * NQ + w] * 0.5f;
        float om = omega[l * NQ + w] * 0.5f;
        float st_, ct, sp, cp, so, co;
        sincosf(th, &st_, &ct);
        sincosf(ph, &sp, &cp);
        sincosf(om, &so, &co);
        // A = RY * RZ ; RZ = diag((ct,-st), (ct,st))
        float A00r = cp * ct, A00i = -cp * st_;
        float A01r = -sp * ct, A01i = -sp * st_;
        float A10r = sp * ct, A10i = -sp * st_;
        float A11r = cp * ct, A11i = cp * st_;
        // V = RX * A ; RX = [[co, -i so], [-i so, co]]
        float V00r = co * A00r + so * A10i, V00i = co * A00i - so * A10r;
        float V01r = co * A01r + so * A11i, V01i = co * A01i - so * A11r;
        float V10r = so * A00i + co * A10r, V10i = -so * A00r + co * A10i;
        float V11r = so * A01i + co * A11r, V11i = -so * A01r + co * A11i;
        if (l == 0) {
            float* G = g8[w];
            G[0] = V00r; G[1] = V00i; G[2] = V01r; G[3] = V01i;
            G[4] = V10r; G[5] = V10i; G[6] = V11r; G[7] = V11i;
        } else {
            float* P = gp[w];
            P[0]  = V00r; P[1]  = V00r; P[2]  = -V00i; P[3]  = V00i;
            P[4]  = V01r; P[5]  = V01r; P[6]  = -V01i; P[7]  = V01i;
            P[8]  = V10r; P[9]  = V10r; P[10] = -V10i; P[11] = V10i;
            P[12] = V11r; P[13] = V11r; P[14] = -V11i; P[15] = V11i;
        }
    }
    __syncthreads();

    int b = blockIdx.x * blockDim.x + tid;
    if (b >= n) return;

    const float2* xr = (const float2*)(x + (size_t)b * 6);
    float2 x01 = xr[0], x23 = xr[1], x45 = xr[2];

    // ---- state: 64 complex amps as one 128-wide register vector, (re,im) pairs.
    // wire w <-> bit (5-w) of the logical index (wire0 = MSB, PennyLane order).
    f128 st;

    // angle-encode + layer-1 gate on local 2-vector, then product-expand
    #pragma unroll
    for (int w = 0; w < NQ; ++w) {
        float xv = (w == 0) ? x01.x : (w == 1) ? x01.y : (w == 2) ? x23.x
                 : (w == 3) ? x23.y : (w == 4) ? x45.x : x45.y;
        xv = fminf(fmaxf(xv, -15.f), 15.f);
        float e = __expf(2.f * xv);
        float t = (e - 1.f) / (e + 1.f);       // tanh
        float a = t * 1.57079632679489662f;    // half-angle = tanh(x)*pi/2
        float s, c;
        __sincosf(a, &s, &c);
        const f2* G2 = (const f2*)g8[w];
        f2 cc = {c, c}, ss = {s, s};
        f2 u0 = F2FMA(cc, G2[0], ss * G2[1]);  // (V00r*c+V01r*s, V00i*c+V01i*s)
        f2 u1 = F2FMA(cc, G2[2], ss * G2[3]);
        if (w == 0) {
            st[0] = u0.x; st[1] = u0.y; st[2] = u1.x; st[3] = u1.y;
        } else {
            f2 u0rr = {u0.x, u0.x}, u0np = {-u0.y, u0.y};
            f2 u1rr = {u1.x, u1.x}, u1np = {-u1.y, u1.y};
            #pragma unroll
            for (int k = (1 << w) - 1; k >= 0; --k) {
                f2 a2 = {st[2 * k], st[2 * k + 1]};
                f2 a2s = {a2.y, a2.x};
                f2 n0 = F2FMA(u0rr, a2, u0np * a2s);   // a * u0 (complex)
                f2 n1 = F2FMA(u1rr, a2, u1np * a2s);   // a * u1
                st[4 * k]     = n0.x; st[4 * k + 1] = n0.y;
                st[4 * k + 2] = n1.x; st[4 * k + 3] = n1.y;
            }
        }
    }

    // ---- layer-1 CNOT ring folded into P1; layer-2 dense gates ----
    #pragma unroll
    for (int w = 0; w < NQ; ++w) {
        const f2* C = (const f2*)gp[w];
        f2 c00r = C[0], c00i = C[1], c01r = C[2], c01i = C[3];
        f2 c10r = C[4], c10i = C[5], c11r = C[6], c11i = C[7];
        const int tb = 1 << (5 - w);
        #pragma unroll
        for (int i = 0; i < DIM; ++i) {
            if (!(i & tb)) {
                const int s0 = PP.P1[i], s1 = PP.P1[i + tb];
                f2 a0 = {st[2 * s0], st[2 * s0 + 1]};
                f2 a1 = {st[2 * s1], st[2 * s1 + 1]};
                f2 a0s = {a0.y, a0.x}, a1s = {a1.y, a1.x};
                f2 r0 = F2FMA(c00r, a0, F2FMA(c00i, a0s, F2FMA(c01r, a1, c01i * a1s)));
                f2 r1 = F2FMA(c10r, a0, F2FMA(c10i, a0s, F2FMA(c11r, a1, c11i * a1s)));
                st[2 * s0] = r0.x; st[2 * s0 + 1] = r0.y;
                st[2 * s1] = r1.x; st[2 * s1 + 1] = r1.y;
            }
        }
    }

    // ---- layer-2 CNOT ring folded into P2; measurement marginals ----
    f16v mh = {0, 0, 0, 0, 0, 0, 0, 0, 0, 0, 0, 0, 0, 0, 0, 0};
    f16v ml = {0, 0, 0, 0, 0, 0, 0, 0, 0, 0, 0, 0, 0, 0, 0, 0};
    #pragma unroll
    for (int l = 0; l < DIM; ++l) {
        const int s = PP.P2[l];
        f2 a = {st[2 * s], st[2 * s + 1]};
        const int h = l >> 3, lo = l & 7;
        f2 bh = {mh[2 * h], mh[2 * h + 1]};
        bh = F2FMA(a, a, bh);
        mh[2 * h] = bh.x; mh[2 * h + 1] = bh.y;
        f2 bl = {ml[2 * lo], ml[2 * lo + 1]};
        bl = F2FMA(a, a, bl);
        ml[2 * lo] = bl.x; ml[2 * lo + 1] = bl.y;
    }
    float B0 = mh[0] + mh[1],  B1 = mh[2] + mh[3],  B2 = mh[4] + mh[5],  B3 = mh[6] + mh[7];
    float B4 = mh[8] + mh[9],  B5 = mh[10] + mh[11], B6 = mh[12] + mh[13], B7 = mh[14] + mh[15];
    float C0 = ml[0] + ml[1],  C1 = ml[2] + ml[3],  C2 = ml[4] + ml[5],  C3 = ml[6] + ml[7];
    float C4 = ml[8] + ml[9],  C5 = ml[10] + ml[11], C6 = ml[12] + ml[13], C7 = ml[14] + ml[15];

    float z0 = (B0 + B1 + B2 + B3) - (B4 + B5 + B6 + B7);
    float z1 = (B0 + B1 + B4 + B5) - (B2 + B3 + B6 + B7);
    float z2 = (B0 + B2 + B4 + B6) - (B1 + B3 + B5 + B7);
    float z3 = (C0 + C1 + C2 + C3) - (C4 + C5 + C6 + C7);
    float z4 = (C0 + C1 + C4 + C5) - (C2 + C3 + C6 + C7);
    float z5 = (C0 + C2 + C4 + C6) - (C1 + C3 + C5 + C7);

    // out[:, k] = z[k % 6], k = 0..7
    float4* o = (float4*)(out + (size_t)b * 8);
    o[0] = make_float4(z0, z1, z2, z3);
    o[1] = make_float4(z4, z5, z0, z1);
}

extern "C" void kernel_launch(void* const* d_in, const int* in_sizes, int n_in,
                              void* d_out, int out_size, void* d_ws, size_t ws_size,
                              hipStream_t stream) {
    const float* x     = (const float*)d_in[0];
    const float* theta = (const float*)d_in[1];
    const float* phi   = (const float*)d_in[2];
    const float* omega = (const float*)d_in[3];
    float* out = (float*)d_out;
    int n = in_sizes[0] / NQ;
    int blocks = (n + 255) / 256;
    hipLaunchKernelGGL(qent_kernel, dim3(blocks), dim3(256), 0, stream,
                       x, theta, phi, omega, out, n);
}

// Round 6
// 15.923 us; speedup vs baseline: 16.5669x; 1.1023x over previous
//
#include <hip/hip_runtime.h>
#include <math.h>

#define NQ 6

typedef _Float16 h8 __attribute__((ext_vector_type(8)));
typedef float f4   __attribute__((ext_vector_type(4)));
typedef float f8v  __attribute__((ext_vector_type(8)));
typedef float f64v __attribute__((ext_vector_type(64)));
typedef unsigned int uint;

__device__ __forceinline__ uint pk2(float a, float b) {
    return __builtin_bit_cast(uint, __builtin_amdgcn_cvt_pkrtz(a, b));
}

// Fused per-(layer,wire) gate V = RX*RY*RZ -> g[l][w][8] = {V00r,V00i,V01r,V01i,V10r,V10i,V11r,V11i}
__device__ __forceinline__ void build_gates(const float* theta, const float* phi,
                                            const float* omega, int tid,
                                            float (*g)[NQ][8]) {
    if (tid < 2 * NQ) {
        int l = tid / NQ, w = tid % NQ;
        float th = theta[l*NQ+w]*0.5f, ph = phi[l*NQ+w]*0.5f, om = omega[l*NQ+w]*0.5f;
        float st_, ct, sp, cp, so, co;
        sincosf(th, &st_, &ct); sincosf(ph, &sp, &cp); sincosf(om, &so, &co);
        float A00r = cp*ct,  A00i = -cp*st_;
        float A01r = -sp*ct, A01i = -sp*st_;
        float A10r = sp*ct,  A10i = -sp*st_;
        float A11r = cp*ct,  A11i = cp*st_;
        float* G = g[l][w];
        G[0] = co*A00r + so*A10i;  G[1] = co*A00i - so*A10r;
        G[2] = co*A01r + so*A11i;  G[3] = co*A01i - so*A11r;
        G[4] = so*A00i + co*A10r;  G[5] = -so*A00r + co*A10i;
        G[6] = so*A01i + co*A11r;  G[7] = -so*A01r + co*A11i;
    }
}

// ---------------- kernel 1: precompute W = circuit unitary (f16, MFMA B-frag layout) ----------------
// Block j (1 wave) simulates basis column e_j; lane i holds amplitude i (complex).
// Consumer (kernel 2) lane l reads frag(ri,kt,nt) element e as B[k][col],
//   k = kt*32 + (l>>4)*8 + e, col = nt*16 + (l&15).  Store: half idx = frag*512 + l*8 + e.
__global__ __launch_bounds__(64) void qent_prep(
    const float* __restrict__ theta, const float* __restrict__ phi,
    const float* __restrict__ omega, _Float16* __restrict__ W)
{
    __shared__ float g[2][NQ][8];
    const int i = threadIdx.x;
    build_gates(theta, phi, omega, i, g);
    __syncthreads();
    const int j = blockIdx.x;
    float ar = (i == j) ? 1.f : 0.f, ai = 0.f;
    #pragma unroll
    for (int l = 0; l < 2; ++l) {
        #pragma unroll
        for (int w = 0; w < NQ; ++w) {                   // dense 2x2 gates
            const int tb = 1 << (5 - w);
            float pr = __shfl_xor(ar, tb);
            float pi = __shfl_xor(ai, tb);
            const float* G = g[l][w];
            const bool hi = (i & tb) != 0;
            float car = hi ? G[6] : G[0], cai = hi ? G[7] : G[1];
            float cpr = hi ? G[4] : G[2], cpi = hi ? G[5] : G[3];
            float nar = car*ar - cai*ai + cpr*pr - cpi*pi;
            float nai = car*ai + cai*ar + cpr*pi + cpi*pr;
            ar = nar; ai = nai;
        }
        #pragma unroll
        for (int w = 0; w < NQ; ++w) {                   // CNOT ring
            const int cb = 1 << (5 - w), tb = 1 << (5 - ((w + 1) % NQ));
            float pr = __shfl_xor(ar, tb);
            float pi = __shfl_xor(ai, tb);
            if (i & cb) { ar = pr; ai = pi; }
        }
    }
    const int kt = j >> 5, e = j & 7;
    const int nt = i >> 4;
    const int slot = ((j >> 3) & 3) * 16 + (i & 15);
    W[(kt*4 + nt)*512 + slot*8 + e]     = (_Float16)ar;
    W[(8 + kt*4 + nt)*512 + slot*8 + e] = (_Float16)ai;
}

// ---------------- kernel 2: encode -> E, GEMM vs W (MFMA), |amp|^2, Z-sums ----------------
#define MFMA(d, a, b) d = __builtin_amdgcn_mfma_f32_16x16x32_f16((a), (b), (d), 0, 0, 0)
// A-frag read: row = mt*16+(lane&15), chunk = (kt*4 + (lane>>4)) XOR-swizzled by row&7 (= lane&7)
#define LDA(mt, kt) (*(const h8*)(wbase + ((mt)*16 + (lane & 15))*128 + (((((kt)*4) + (lane >> 4)) ^ (lane & 7)) << 4)))

__global__ __launch_bounds__(256, 2) void qent_main(
    const float* __restrict__ x, const _Float16* __restrict__ Wp,
    float* __restrict__ out, int n)
{
    __shared__ f4 ldsbuf[4096];          // 64 KiB: per-wave 16 KiB region (E 8K overlaid by partials 16K)
    char* lds = (char*)ldsbuf;
    const int tid = threadIdx.x;
    const int lane = tid & 63;
    char* wbase = lds + ((tid >> 6) << 14);
    const int gid = blockIdx.x * 256 + tid;

    // --- W fragments: 16 coalesced dwordx4 loads (L2-resident after first wave) ---
    const h8* Wv = (const h8*)Wp;
    h8 WR00 = Wv[ 0*64+lane], WR01 = Wv[ 1*64+lane], WR02 = Wv[ 2*64+lane], WR03 = Wv[ 3*64+lane];
    h8 WR10 = Wv[ 4*64+lane], WR11 = Wv[ 5*64+lane], WR12 = Wv[ 6*64+lane], WR13 = Wv[ 7*64+lane];
    h8 WI00 = Wv[ 8*64+lane], WI01 = Wv[ 9*64+lane], WI02 = Wv[10*64+lane], WI03 = Wv[11*64+lane];
    h8 WI10 = Wv[12*64+lane], WI11 = Wv[13*64+lane], WI12 = Wv[14*64+lane], WI13 = Wv[15*64+lane];

    // --- encode: (c_w, s_w) = (cos, sin)(tanh(x)*pi/2) ---
    const int sidx = (gid < n) ? gid : (n - 1);
    const float2* xr = (const float2*)(x + (size_t)sidx * 6);
    float2 x01 = xr[0], x23 = xr[1], x45 = xr[2];
    f8v CW, SW;
    #pragma unroll
    for (int w = 0; w < 6; ++w) {
        float xv = (w == 0) ? x01.x : (w == 1) ? x01.y : (w == 2) ? x23.x
                 : (w == 3) ? x23.y : (w == 4) ? x45.x : x45.y;
        xv = fminf(fmaxf(xv, -15.f), 15.f);
        float e2 = __expf(2.f * xv);
        float t = (e2 - 1.f) / (e2 + 1.f);
        float a = t * 1.57079632679489662f;
        float sv, cv;
        __sincosf(a, &sv, &cv);
        CW[w] = cv; SW[w] = sv;
    }

    // --- product expansion: E_j = prod_w (bit(5-w) of j ? s_w : c_w), real, register-resident ---
    f64v E;
    E[0] = CW[0]; E[1] = SW[0];
    #pragma unroll
    for (int w = 1; w < 6; ++w) {
        #pragma unroll
        for (int k = (1 << w) - 1; k >= 0; --k) {
            float a = E[k];
            E[2*k]   = a * CW[w];
            E[2*k+1] = a * SW[w];
        }
    }

    // --- pack f16, write own LDS row (128 B), chunk XOR-swizzle (chunk ^ (row&7)) for bank spread ---
    #pragma unroll
    for (int k = 0; k < 8; ++k) {
        uint4 q;
        q.x = pk2(E[8*k+0], E[8*k+1]);
        q.y = pk2(E[8*k+2], E[8*k+3]);
        q.z = pk2(E[8*k+4], E[8*k+5]);
        q.w = pk2(E[8*k+6], E[8*k+7]);
        *(uint4*)(wbase + lane*128 + ((k ^ (lane & 7)) << 4)) = q;
    }
    __syncthreads();

    // --- GEMM: F = E @ W  (M=64 samples, N=64 amps, K=64), real then imag pass ---
    f4 c00={0,0,0,0}, c01={0,0,0,0}, c02={0,0,0,0}, c03={0,0,0,0};
    f4 c10={0,0,0,0}, c11={0,0,0,0}, c12={0,0,0,0}, c13={0,0,0,0};
    f4 c20={0,0,0,0}, c21={0,0,0,0}, c22={0,0,0,0}, c23={0,0,0,0};
    f4 c30={0,0,0,0}, c31={0,0,0,0}, c32={0,0,0,0}, c33={0,0,0,0};
    {   // real pass, kt = 0
        h8 A0 = LDA(0,0), A1 = LDA(1,0), A2 = LDA(2,0), A3 = LDA(3,0);
        MFMA(c00,A0,WR00); MFMA(c01,A0,WR01); MFMA(c02,A0,WR02); MFMA(c03,A0,WR03);
        MFMA(c10,A1,WR00); MFMA(c11,A1,WR01); MFMA(c12,A1,WR02); MFMA(c13,A1,WR03);
        MFMA(c20,A2,WR00); MFMA(c21,A2,WR01); MFMA(c22,A2,WR02); MFMA(c23,A2,WR03);
        MFMA(c30,A3,WR00); MFMA(c31,A3,WR01); MFMA(c32,A3,WR02); MFMA(c33,A3,WR03);
    }
    {   // real pass, kt = 1
        h8 A0 = LDA(0,1), A1 = LDA(1,1), A2 = LDA(2,1), A3 = LDA(3,1);
        MFMA(c00,A0,WR10); MFMA(c01,A0,WR11); MFMA(c02,A0,WR12); MFMA(c03,A0,WR13);
        MFMA(c10,A1,WR10); MFMA(c11,A1,WR11); MFMA(c12,A1,WR12); MFMA(c13,A1,WR13);
        MFMA(c20,A2,WR10); MFMA(c21,A2,WR11); MFMA(c22,A2,WR12); MFMA(c23,A2,WR13);
        MFMA(c30,A3,WR10); MFMA(c31,A3,WR11); MFMA(c32,A3,WR12); MFMA(c33,A3,WR13);
    }
    f4 p00 = c00*c00, p01 = c01*c01, p02 = c02*c02, p03 = c03*c03;
    f4 p10 = c10*c10, p11 = c11*c11, p12 = c12*c12, p13 = c13*c13;
    f4 p20 = c20*c20, p21 = c21*c21, p22 = c22*c22, p23 = c23*c23;
    f4 p30 = c30*c30, p31 = c31*c31, p32 = c32*c32, p33 = c33*c33;
    c00=(f4){0,0,0,0}; c01=(f4){0,0,0,0}; c02=(f4){0,0,0,0}; c03=(f4){0,0,0,0};
    c10=(f4){0,0,0,0}; c11=(f4){0,0,0,0}; c12=(f4){0,0,0,0}; c13=(f4){0,0,0,0};
    c20=(f4){0,0,0,0}; c21=(f4){0,0,0,0}; c22=(f4){0,0,0,0}; c23=(f4){0,0,0,0};
    c30=(f4){0,0,0,0}; c31=(f4){0,0,0,0}; c32=(f4){0,0,0,0}; c33=(f4){0,0,0,0};
    {   // imag pass, kt = 0
        h8 A0 = LDA(0,0), A1 = LDA(1,0), A2 = LDA(2,0), A3 = LDA(3,0);
        MFMA(c00,A0,WI00); MFMA(c01,A0,WI01); MFMA(c02,A0,WI02); MFMA(c03,A0,WI03);
        MFMA(c10,A1,WI00); MFMA(c11,A1,WI01); MFMA(c12,A1,WI02); MFMA(c13,A1,WI03);
        MFMA(c20,A2,WI00); MFMA(c21,A2,WI01); MFMA(c22,A2,WI02); MFMA(c23,A2,WI03);
        MFMA(c30,A3,WI00); MFMA(c31,A3,WI01); MFMA(c32,A3,WI02); MFMA(c33,A3,WI03);
    }
    {   // imag pass, kt = 1
        h8 A0 = LDA(0,1), A1 = LDA(1,1), A2 = LDA(2,1), A3 = LDA(3,1);
        MFMA(c00,A0,WI10); MFMA(c01,A0,WI11); MFMA(c02,A0,WI12); MFMA(c03,A0,WI13);
        MFMA(c10,A1,WI10); MFMA(c11,A1,WI11); MFMA(c12,A1,WI12); MFMA(c13,A1,WI13);
        MFMA(c20,A2,WI10); MFMA(c21,A2,WI11); MFMA(c22,A2,WI12); MFMA(c23,A2,WI13);
        MFMA(c30,A3,WI10); MFMA(c31,A3,WI11); MFMA(c32,A3,WI12); MFMA(c33,A3,WI13);
    }
    p00 += c00*c00; p01 += c01*c01; p02 += c02*c02; p03 += c03*c03;
    p10 += c10*c10; p11 += c11*c11; p12 += c12*c12; p13 += c13*c13;
    p20 += c20*c20; p21 += c21*c21; p22 += c22*c22; p23 += c23*c23;
    p30 += c30*c30; p31 += c31*c31; p32 += c32*c32; p33 += c33*c33;
    __syncthreads();   // all A-frag reads done; safe to overlay partials on E region

    // --- partials {tot, z0p, z1p} per (sample, col) -> LDS (col XOR-swizzled by s&15) ---
    // amp = nt*16 + col: wire0 sign = nt>=2, wire1 sign = nt&1, wires2..5 = col bits 3..0
#define PART(mt, r) { \
        float q0 = p##mt##0[r], q1 = p##mt##1[r], q2 = p##mt##2[r], q3 = p##mt##3[r]; \
        float a_ = q0 + q1, b_ = q2 + q3; \
        int s_ = (mt)*16 + (lane >> 4)*4 + (r); \
        *(f4*)(wbase + s_*256 + ((((lane & 15)) ^ (s_ & 15)) << 4)) = \
            (f4){a_ + b_, a_ - b_, (q0 - q1) + (q2 - q3), 0.f}; \
    }
    PART(0,0) PART(0,1) PART(0,2) PART(0,3)
    PART(1,0) PART(1,1) PART(1,2) PART(1,3)
    PART(2,0) PART(2,1) PART(2,2) PART(2,3)
    PART(3,0) PART(3,1) PART(3,2) PART(3,3)
#undef PART
    __syncthreads();

    // --- finish: each thread sums its own sample's 16 col-partials with compile-time signs ---
    float z0=0.f, z1=0.f, z2=0.f, z3=0.f, z4=0.f, z5=0.f;
    #pragma unroll
    for (int c = 0; c < 16; ++c) {
        f4 rec = *(const f4*)(wbase + lane*256 + ((c ^ (lane & 15)) << 4));
        z0 += rec.y; z1 += rec.z;
        float tot = rec.x;
        z2 += (c & 8) ? -tot : tot;
        z3 += (c & 4) ? -tot : tot;
        z4 += (c & 2) ? -tot : tot;
        z5 += (c & 1) ? -tot : tot;
    }
    if (gid < n) {
        float4* o = (float4*)(out + (size_t)gid * 8);
        o[0] = make_float4(z0, z1, z2, z3);
        o[1] = make_float4(z4, z5, z0, z1);
    }
}

extern "C" void kernel_launch(void* const* d_in, const int* in_sizes, int n_in,
                              void* d_out, int out_size, void* d_ws, size_t ws_size,
                              hipStream_t stream) {
    const float* x     = (const float*)d_in[0];
    const float* theta = (const float*)d_in[1];
    const float* phi   = (const float*)d_in[2];
    const float* omega = (const float*)d_in[3];
    float* out = (float*)d_out;
    _Float16* W = (_Float16*)d_ws;      // 16 KiB: 16 frags x 1 KiB
    int n = in_sizes[0] / NQ;
    hipLaunchKernelGGL(qent_prep, dim3(64), dim3(64), 0, stream, theta, phi, omega, W);
    int blocks = (n + 255) / 256;
    hipLaunchKernelGGL(qent_main, dim3(blocks), dim3(256), 0, stream, x, W, out, n);
}

// Round 7
// 15.910 us; speedup vs baseline: 16.5803x; 1.0008x over previous
//
#include <hip/hip_runtime.h>
#include <math.h>

#define NQ 6

typedef _Float16 h8 __attribute__((ext_vector_type(8)));
typedef float f4   __attribute__((ext_vector_type(4)));
typedef float f8v  __attribute__((ext_vector_type(8)));
typedef float f64v __attribute__((ext_vector_type(64)));
typedef unsigned int uint;

__device__ __forceinline__ uint pk2(float a, float b) {
    return __builtin_bit_cast(uint, __builtin_amdgcn_cvt_pkrtz(a, b));
}

__device__ __forceinline__ void build_gates(const float* theta, const float* phi,
                                            const float* omega, int tid,
                                            float (*g)[NQ][8]) {
    if (tid < 2 * NQ) {
        int l = tid / NQ, w = tid % NQ;
        float th = theta[l*NQ+w]*0.5f, ph = phi[l*NQ+w]*0.5f, om = omega[l*NQ+w]*0.5f;
        float st_, ct, sp, cp, so, co;
        sincosf(th, &st_, &ct); sincosf(ph, &sp, &cp); sincosf(om, &so, &co);
        float A00r = cp*ct,  A00i = -cp*st_;
        float A01r = -sp*ct, A01i = -sp*st_;
        float A10r = sp*ct,  A10i = -sp*st_;
        float A11r = cp*ct,  A11i = cp*st_;
        float* G = g[l][w];
        G[0] = co*A00r + so*A10i;  G[1] = co*A00i - so*A10r;
        G[2] = co*A01r + so*A11i;  G[3] = co*A01i - so*A11r;
        G[4] = so*A00i + co*A10r;  G[5] = -so*A00r + co*A10i;
        G[6] = so*A01i + co*A11r;  G[7] = -so*A01r + co*A11i;
    }
}

__global__ __launch_bounds__(64) void qent_prep(
    const float* __restrict__ theta, const float* __restrict__ phi,
    const float* __restrict__ omega, _Float16* __restrict__ W)
{
    __shared__ float g[2][NQ][8];
    const int i = threadIdx.x;
    build_gates(theta, phi, omega, i, g);
    __syncthreads();
    const int j = blockIdx.x;
    float ar = (i == j) ? 1.f : 0.f, ai = 0.f;
    #pragma unroll
    for (int l = 0; l < 2; ++l) {
        #pragma unroll
        for (int w = 0; w < NQ; ++w) {
            const int tb = 1 << (5 - w);
            float pr = __shfl_xor(ar, tb);
            float pi = __shfl_xor(ai, tb);
            const float* G = g[l][w];
            const bool hi = (i & tb) != 0;
            float car = hi ? G[6] : G[0], cai = hi ? G[7] : G[1];
            float cpr = hi ? G[4] : G[2], cpi = hi ? G[5] : G[3];
            float nar = car*ar - cai*ai + cpr*pr - cpi*pi;
            float nai = car*ai + cai*ar + cpr*pi + cpi*pr;
            ar = nar; ai = nai;
        }
        #pragma unroll
        for (int w = 0; w < NQ; ++w) {
            const int cb = 1 << (5 - w), tb = 1 << (5 - ((w + 1) % NQ));
            float pr = __shfl_xor(ar, tb);
            float pi = __shfl_xor(ai, tb);
            if (i & cb) { ar = pr; ai = pi; }
        }
    }
    const int kt = j >> 5, e = j & 7;
    const int nt = i >> 4;
    const int slot = ((j >> 3) & 3) * 16 + (i & 15);
    W[(kt*4 + nt)*512 + slot*8 + e]     = (_Float16)ar;
    W[(8 + kt*4 + nt)*512 + slot*8 + e] = (_Float16)ai;
}

#define MFMA(d, a, b) d = __builtin_amdgcn_mfma_f32_16x16x32_f16((a), (b), (d), 0, 0, 0)
#define LDA(mt, kt) (*(const h8*)(wbase + ((mt)*16 + (lane & 15))*128 + (((((kt)*4) + (lane >> 4)) ^ (lane & 7)) << 4)))

__global__ __launch_bounds__(256, 2) void qent_main(
    const float* __restrict__ x, const _Float16* __restrict__ Wp,
    float* __restrict__ out, int n)
{
    __shared__ f4 ldsbuf[4096];
    char* lds = (char*)ldsbuf;
    const int tid = threadIdx.x;
    const int lane = tid & 63;
    char* wbase = lds + ((tid >> 6) << 14);
    const int gid = blockIdx.x * 256 + tid;

    const h8* Wv = (const h8*)Wp;
    h8 WR00 = Wv[ 0*64+lane], WR01 = Wv[ 1*64+lane], WR02 = Wv[ 2*64+lane], WR03 = Wv[ 3*64+lane];
    h8 WR10 = Wv[ 4*64+lane], WR11 = Wv[ 5*64+lane], WR12 = Wv[ 6*64+lane], WR13 = Wv[ 7*64+lane];
    h8 WI00 = Wv[ 8*64+lane], WI01 = Wv[ 9*64+lane], WI02 = Wv[10*64+lane], WI03 = Wv[11*64+lane];
    h8 WI10 = Wv[12*64+lane], WI11 = Wv[13*64+lane], WI12 = Wv[14*64+lane], WI13 = Wv[15*64+lane];

    const int sidx = (gid < n) ? gid : (n - 1);
    const float2* xr = (const float2*)(x + (size_t)sidx * 6);
    float2 x01 = xr[0], x23 = xr[1], x45 = xr[2];
    f8v CW, SW;
    #pragma unroll
    for (int w = 0; w < 6; ++w) {
        float xv = (w == 0) ? x01.x : (w == 1) ? x01.y : (w == 2) ? x23.x
                 : (w == 3) ? x23.y : (w == 4) ? x45.x : x45.y;
        xv = fminf(fmaxf(xv, -15.f), 15.f);
        float e2 = __expf(2.f * xv);
        float t = (e2 - 1.f) / (e2 + 1.f);
        float a = t * 1.57079632679489662f;
        float sv, cv;
        __sincosf(a, &sv, &cv);
        CW[w] = cv; SW[w] = sv;
    }

    f64v E;
    E[0] = CW[0]; E[1] = SW[0];
    #pragma unroll
    for (int w = 1; w < 6; ++w) {
        #pragma unroll
        for (int k = (1 << w) - 1; k >= 0; --k) {
            float a = E[k];
            E[2*k]   = a * CW[w];
            E[2*k+1] = a * SW[w];
        }
    }

    #pragma unroll
    for (int k = 0; k < 8; ++k) {
        uint4 q;
        q.x = pk2(E[8*k+0], E[8*k+1]);
        q.y = pk2(E[8*k+2], E[8*k+3]);
        q.z = pk2(E[8*k+4], E[8*k+5]);
        q.w = pk2(E[8*k+6], E[8*k+7]);
        *(uint4*)(wbase + lane*128 + ((k ^ (lane & 7)) << 4)) = q;
    }
    __syncthreads();

    // A-frags loaded ONCE (8 reads), reused by real and imag passes
    h8 A00 = LDA(0,0), A10 = LDA(1,0), A20 = LDA(2,0), A30 = LDA(3,0);
    h8 A01 = LDA(0,1), A11 = LDA(1,1), A21 = LDA(2,1), A31 = LDA(3,1);

    f4 c00={0,0,0,0}, c01={0,0,0,0}, c02={0,0,0,0}, c03={0,0,0,0};
    f4 c10={0,0,0,0}, c11={0,0,0,0}, c12={0,0,0,0}, c13={0,0,0,0};
    f4 c20={0,0,0,0}, c21={0,0,0,0}, c22={0,0,0,0}, c23={0,0,0,0};
    f4 c30={0,0,0,0}, c31={0,0,0,0}, c32={0,0,0,0}, c33={0,0,0,0};
    MFMA(c00,A00,WR00); MFMA(c01,A00,WR01); MFMA(c02,A00,WR02); MFMA(c03,A00,WR03);
    MFMA(c10,A10,WR00); MFMA(c11,A10,WR01); MFMA(c12,A10,WR02); MFMA(c13,A10,WR03);
    MFMA(c20,A20,WR00); MFMA(c21,A20,WR01); MFMA(c22,A20,WR02); MFMA(c23,A20,WR03);
    MFMA(c30,A30,WR00); MFMA(c31,A30,WR01); MFMA(c32,A30,WR02); MFMA(c33,A30,WR03);
    MFMA(c00,A01,WR10); MFMA(c01,A01,WR11); MFMA(c02,A01,WR12); MFMA(c03,A01,WR13);
    MFMA(c10,A11,WR10); MFMA(c11,A11,WR11); MFMA(c12,A11,WR12); MFMA(c13,A11,WR13);
    MFMA(c20,A21,WR10); MFMA(c21,A21,WR11); MFMA(c22,A21,WR12); MFMA(c23,A21,WR13);
    MFMA(c30,A31,WR10); MFMA(c31,A31,WR11); MFMA(c32,A31,WR12); MFMA(c33,A31,WR13);
    f4 p00 = c00*c00, p01 = c01*c01, p02 = c02*c02, p03 = c03*c03;
    f4 p10 = c10*c10, p11 = c11*c11, p12 = c12*c12, p13 = c13*c13;
    f4 p20 = c20*c20, p21 = c21*c21, p22 = c22*c22, p23 = c23*c23;
    f4 p30 = c30*c30, p31 = c31*c31, p32 = c32*c32, p33 = c33*c33;
    c00=(f4){0,0,0,0}; c01=(f4){0,0,0,0}; c02=(f4){0,0,0,0}; c03=(f4){0,0,0,0};
    c10=(f4){0,0,0,0}; c11=(f4){0,0,0,0}; c12=(f4){0,0,0,0}; c13=(f4){0,0,0,0};
    c20=(f4){0,0,0,0}; c21=(f4){0,0,0,0}; c22=(f4){0,0,0,0}; c23=(f4){0,0,0,0};
    c30=(f4){0,0,0,0}; c31=(f4){0,0,0,0}; c32=(f4){0,0,0,0}; c33=(f4){0,0,0,0};
    MFMA(c00,A00,WI00); MFMA(c01,A00,WI01); MFMA(c02,A00,WI02); MFMA(c03,A00,WI03);
    MFMA(c10,A10,WI00); MFMA(c11,A10,WI01); MFMA(c12,A10,WI02); MFMA(c13,A10,WI03);
    MFMA(c20,A20,WI00); MFMA(c21,A20,WI01); MFMA(c22,A20,WI02); MFMA(c23,A20,WI03);
    MFMA(c30,A30,WI00); MFMA(c31,A30,WI01); MFMA(c32,A30,WI02); MFMA(c33,A30,WI03);
    MFMA(c00,A01,WI10); MFMA(c01,A01,WI11); MFMA(c02,A01,WI12); MFMA(c03,A01,WI13);
    MFMA(c10,A11,WI10); MFMA(c11,A11,WI11); MFMA(c12,A11,WI12); MFMA(c13,A11,WI13);
    MFMA(c20,A21,WI10); MFMA(c21,A21,WI11); MFMA(c22,A21,WI12); MFMA(c23,A21,WI13);
    MFMA(c30,A31,WI10); MFMA(c31,A31,WI11); MFMA(c32,A31,WI12); MFMA(c33,A31,WI13);
    p00 += c00*c00; p01 += c01*c01; p02 += c02*c02; p03 += c03*c03;
    p10 += c10*c10; p11 += c11*c11; p12 += c12*c12; p13 += c13*c13;
    p20 += c20*c20; p21 += c21*c21; p22 += c22*c22; p23 += c23*c23;
    p30 += c30*c30; p31 += c31*c31; p32 += c32*c32; p33 += c33*c33;
    __syncthreads();

#define PART(mt, r) { \
        float q0 = p##mt##0[r], q1 = p##mt##1[r], q2 = p##mt##2[r], q3 = p##mt##3[r]; \
        float a_ = q0 + q1, b_ = q2 + q3; \
        int s_ = (mt)*16 + (lane >> 4)*4 + (r); \
        *(f4*)(wbase + s_*256 + ((((lane & 15)) ^ (s_ & 15)) << 4)) = \
            (f4){a_ + b_, a_ - b_, (q0 - q1) + (q2 - q3), 0.f}; \
    }
    PART(0,0) PART(0,1) PART(0,2) PART(0,3)
    PART(1,0) PART(1,1) PART(1,2) PART(1,3)
    PART(2,0) PART(2,1) PART(2,2) PART(2,3)
    PART(3,0) PART(3,1) PART(3,2) PART(3,3)
#undef PART
    __syncthreads();

    float z0=0.f, z1=0.f, z2=0.f, z3=0.f, z4=0.f, z5=0.f;
    #pragma unroll
    for (int c = 0; c < 16; ++c) {
        f4 rec = *(const f4*)(wbase + lane*256 + ((c ^ (lane & 15)) << 4));
        z0 += rec.y; z1 += rec.z;
        float tot = rec.x;
        z2 += (c & 8) ? -tot : tot;
        z3 += (c & 4) ? -tot : tot;
        z4 += (c & 2) ? -tot : tot;
        z5 += (c & 1) ? -tot : tot;
    }
    if (gid < n) {
        float4* o = (float4*)(out + (size_t)gid * 8);
        o[0] = make_float4(z0, z1, z2, z3);
        o[1] = make_float4(z4, z5, z0, z1);
    }
}

extern "C" void kernel_launch(void* const* d_in, const int* in_sizes, int n_in,
                              void* d_out, int out_size, void* d_ws, size_t ws_size,
                              hipStream_t stream) {
    const float* x     = (const float*)d_in[0];
    const float* theta = (const float*)d_in[1];
    const float* phi   = (const float*)d_in[2];
    const float* omega = (const float*)d_in[3];
    float* out = (float*)d_out;
    _Float16* W = (_Float16*)d_ws;
    int n = in_sizes[0] / NQ;
    hipLaunchKernelGGL(qent_prep, dim3(64), dim3(64), 0, stream, theta, phi, omega, W);
    int blocks = (n + 255) / 256;
    hipLaunchKernelGGL(qent_main, dim3(blocks), dim3(256), 0, stream, x, W, out, n);
}